// Round 7
// baseline (507.455 us; speedup 1.0000x reference)
//
#include <hip/hip_runtime.h>

// Atom_embedding_MP: B=4, N=100000, K=16, D=6, C_IN=13, 3 layers.
// Round-7: break the scalar-load (weight) dependency stalls.
//  Cross-round evidence: dur scales with FMAs-per-weight-fetch (R2:16->112us,
//  R3:8->102us, R6:4->264us). Weights are uniform s_loads; a full layer
//  (169+78 dwords) never fits the ~102-SGPR file, so the compiler interleaves
//  s_load+lgkmcnt waits inside the math. Fix: split output channels d into
//  7+6 so the inner weight block is 49/42 uniform dwords -> batch s_loads
//  into SGPRs ONCE per half-layer, then 8 neighbors x 49 FMAs run stall-free.
//  Features re-read per half from L1/L2 (hot, prefetchable VMEM).
//  2 threads/point; pair-reduce via __shfl_xor(.,1); lrelu via 0.6x+0.4|x|.
//  __launch_bounds__(256,6): 84-VGPR cap, est live ~70 -> 6 waves/SIMD.

constexpr int DD  = 6;
constexpr int KK  = 16;
constexpr int CIN = 13;
constexpr float EPSV = 1e-5f;

__global__ __launch_bounds__(256, 6) void atom_mp(
    const float* __restrict__ dist,   // [P, K]
    const float* __restrict__ at,     // [P, K, D]
    const float* __restrict__ W1,     // [3, CIN, CIN]
    const float* __restrict__ b1,     // [3, CIN]
    const float* __restrict__ W2,     // [3, CIN, D]
    const float* __restrict__ b2,     // [3, D]
    const float* __restrict__ gw,     // [3, D]
    const float* __restrict__ gb,     // [3, D]
    float* __restrict__ out,          // [P, D]
    int P)
{
    int t = blockIdx.x * 256 + threadIdx.x;
    int p = t >> 1;      // point index
    int h = t & 1;       // neighbor half (8 neighbors each)
    if (p >= P) return;

    const float* fa = at   + (long)p * (KK * DD) + h * 48;  // 8 x 6 feats
    const float* fd = dist + (long)p * KK + h * 8;          // 8 dists

    float pe[DD] = {1.f, 1.f, 1.f, 1.f, 1.f, 1.f};

    #pragma unroll 1
    for (int L = 0; L < 3; ++L) {
        const float* w1  = W1 + L * CIN * CIN;
        const float* w2  = W2 + L * CIN * DD;
        const float* bb1 = b1 + L * CIN;
        const float* bb2 = b2 + L * DD;
        const float* gwp = gw + L * DD;
        const float* gbp = gb + L * DD;

        // ---- base[d] = b1[d] + pe @ W1[0:6, d] ----
        float base[CIN];
        #pragma unroll
        for (int d = 0; d < CIN; ++d) {
            float s = bb1[d];
            #pragma unroll
            for (int c = 0; c < DD; ++c)
                s = fmaf(pe[c], w1[c * CIN + d], s);
            base[d] = s;
        }

        float hsum[CIN];

        // ================= half A: output channels d = 0..6 =================
        {
            // 49 uniform dwords -> SGPR-resident block, loaded once
            float wv[7][7];
            #pragma unroll
            for (int j = 0; j < 7; ++j)
                #pragma unroll
                for (int d = 0; d < 7; ++d)
                    wv[j][d] = w1[(6 + j) * CIN + d];

            float hs[7] = {0.f, 0.f, 0.f, 0.f, 0.f, 0.f, 0.f};

            #pragma unroll
            for (int kp = 0; kp < 4; ++kp) {   // neighbor pairs
                float4 q0 = *reinterpret_cast<const float4*>(fa + kp * 12);
                float4 q1 = *reinterpret_cast<const float4*>(fa + kp * 12 + 4);
                float4 q2 = *reinterpret_cast<const float4*>(fa + kp * 12 + 8);
                float2 dq = *reinterpret_cast<const float2*>(fd + kp * 2);
                float f0[7] = {q0.x, q0.y, q0.z, q0.w, q1.x, q1.y, dq.x};
                float f1[7] = {q1.z, q1.w, q2.x, q2.y, q2.z, q2.w, dq.y};

                #pragma unroll
                for (int d = 0; d < 7; ++d) {
                    float x0 = base[d];
                    float x1 = base[d];
                    #pragma unroll
                    for (int j = 0; j < 7; ++j) {
                        x0 = fmaf(f0[j], wv[j][d], x0);
                        x1 = fmaf(f1[j], wv[j][d], x1);
                    }
                    float s = hs[d];
                    s = fmaf(0.6f, x0, s);
                    s = fmaf(0.4f, __builtin_fabsf(x0), s);
                    s = fmaf(0.6f, x1, s);
                    s = fmaf(0.4f, __builtin_fabsf(x1), s);
                    hs[d] = s;
                }
            }
            #pragma unroll
            for (int d = 0; d < 7; ++d) hsum[d] = hs[d];
        }

        // ================= half B: output channels d = 7..12 ================
        {
            float wv[7][6];
            #pragma unroll
            for (int j = 0; j < 7; ++j)
                #pragma unroll
                for (int d = 0; d < 6; ++d)
                    wv[j][d] = w1[(6 + j) * CIN + 7 + d];

            float hs[6] = {0.f, 0.f, 0.f, 0.f, 0.f, 0.f};

            #pragma unroll
            for (int kp = 0; kp < 4; ++kp) {
                float4 q0 = *reinterpret_cast<const float4*>(fa + kp * 12);
                float4 q1 = *reinterpret_cast<const float4*>(fa + kp * 12 + 4);
                float4 q2 = *reinterpret_cast<const float4*>(fa + kp * 12 + 8);
                float2 dq = *reinterpret_cast<const float2*>(fd + kp * 2);
                float f0[7] = {q0.x, q0.y, q0.z, q0.w, q1.x, q1.y, dq.x};
                float f1[7] = {q1.z, q1.w, q2.x, q2.y, q2.z, q2.w, dq.y};

                #pragma unroll
                for (int d = 0; d < 6; ++d) {
                    float x0 = base[7 + d];
                    float x1 = base[7 + d];
                    #pragma unroll
                    for (int j = 0; j < 7; ++j) {
                        x0 = fmaf(f0[j], wv[j][d], x0);
                        x1 = fmaf(f1[j], wv[j][d], x1);
                    }
                    float s = hs[d];
                    s = fmaf(0.6f, x0, s);
                    s = fmaf(0.4f, __builtin_fabsf(x0), s);
                    s = fmaf(0.6f, x1, s);
                    s = fmaf(0.4f, __builtin_fabsf(x1), s);
                    hs[d] = s;
                }
            }
            #pragma unroll
            for (int d = 0; d < 6; ++d) hsum[7 + d] = hs[d];
        }

        // ---- pair-reduce over the two half-threads of this point ----
        #pragma unroll
        for (int d = 0; d < CIN; ++d)
            hsum[d] += __shfl_xor(hsum[d], 1, 64);

        // ---- msg = hsum @ W2 + 16*b2  (both lanes, redundantly) ----
        float msg[DD];
        #pragma unroll
        for (int d = 0; d < DD; ++d) {
            float m = 16.f * bb2[d];
            #pragma unroll
            for (int c = 0; c < CIN; ++c)
                m = fmaf(hsum[c], w2[c * DD + d], m);
            msg[d] = m;
        }

        // ---- GroupNorm(2 groups of 3) + affine + lrelu, residual ----
        #pragma unroll
        for (int g = 0; g < 2; ++g) {
            float m0 = msg[3 * g], m1 = msg[3 * g + 1], m2 = msg[3 * g + 2];
            float mu = (m0 + m1 + m2) * (1.f / 3.f);
            float d0 = m0 - mu, d1 = m1 - mu, d2 = m2 - mu;
            float var = (d0 * d0 + d1 * d1 + d2 * d2) * (1.f / 3.f);
            float rs = rsqrtf(var + EPSV);
            float dv[3] = {d0, d1, d2};
            #pragma unroll
            for (int c = 0; c < 3; ++c) {
                int ch = 3 * g + c;
                float xn = fmaf(dv[c] * rs, gwp[ch], gbp[ch]);
                pe[ch] = fmaf(0.6f, xn, pe[ch]);
                pe[ch] = fmaf(0.4f, __builtin_fabsf(xn), pe[ch]);
            }
        }
    }

    // both lanes hold identical pe; split the 6-float store across the pair
    float* op = out + (long)p * DD;
    if (h == 0) {
        *reinterpret_cast<float2*>(op)     = make_float2(pe[0], pe[1]);
        *reinterpret_cast<float2*>(op + 2) = make_float2(pe[2], pe[3]);
    } else {
        *reinterpret_cast<float2*>(op + 4) = make_float2(pe[4], pe[5]);
    }
}

extern "C" void kernel_launch(void* const* d_in, const int* in_sizes, int n_in,
                              void* d_out, int out_size, void* d_ws, size_t ws_size,
                              hipStream_t stream) {
    const float* dist = (const float*)d_in[0];
    const float* at   = (const float*)d_in[1];
    const float* W1   = (const float*)d_in[2];
    const float* b1   = (const float*)d_in[3];
    const float* W2   = (const float*)d_in[4];
    const float* b2   = (const float*)d_in[5];
    const float* gw   = (const float*)d_in[6];
    const float* gb   = (const float*)d_in[7];
    float* out = (float*)d_out;

    int P = in_sizes[0] / KK;            // dist is [P, K]
    long threads_total = 2L * P;
    int blocks = (int)((threads_total + 255) / 256);
    atom_mp<<<blocks, 256, 0, stream>>>(dist, at, W1, b1, W2, b2, gw, gb, out, P);
}